// Round 1
// baseline (2108.561 us; speedup 1.0000x reference)
//
#include <hip/hip_runtime.h>
#include <hip/hip_bf16.h>

// Problem dims (fixed by reference)
#define T_TOT 256
#define S_TOT 2048
#define C_IN  128
#define HID_  32
#define G_    64
#define L_    64
// T-chunking: h_proj chunk lives in d_ws (TC*S*G*4 = 32 MB)
#define TC    64
#define NCHUNK (T_TOT / TC)

__device__ __forceinline__ float lrelu(float v) { return v >= 0.f ? v : 0.01f * v; }

__device__ __forceinline__ float sigf(float x) {
    x = fminf(fmaxf(x, -30.f), 30.f);
    return __builtin_amdgcn_rcpf(1.f + __expf(-x));
}
__device__ __forceinline__ float tanhf_(float x) {
    x = fminf(fmaxf(x, -15.f), 15.f);
    float e = __expf(-2.f * x);
    return (1.f - e) * __builtin_amdgcn_rcpf(1.f + e);
}

#define FMA4(acc, v, wv)               \
    acc = fmaf((v).x, (wv).x, acc);    \
    acc = fmaf((v).y, (wv).y, acc);    \
    acc = fmaf((v).z, (wv).z, acc);    \
    acc = fmaf((v).w, (wv).w, acc)

// ---------------------------------------------------------------------------
// Kernel A: MLP projection for one T-chunk.  rows = TC*S, 64 rows per block.
// thread (g = tid/32 rowgroup, j = tid%32); W1 col j + W2 cols {j, j+32} in regs.
// ---------------------------------------------------------------------------
__global__ __launch_bounds__(256, 2)
void mlp_kernel(const float* __restrict__ x,     // chunk base: x + c*TC*S*C
                const float* __restrict__ W1, const float* __restrict__ b1,
                const float* __restrict__ W2, const float* __restrict__ b2,
                float* __restrict__ hp)          // [TC*S][G_]
{
    __shared__ float xt[64][C_IN];    // 32 KB
    __shared__ float h1t[64][HID_];   // 8 KB
    const int tid = threadIdx.x;
    const int g = tid >> 5, j = tid & 31;
    const size_t row0 = (size_t)blockIdx.x * 64;

    // stage x tile (coalesced: contiguous 32 KB block)
    {
        const float4* src = (const float4*)(x + row0 * C_IN);
        float4* dst = (float4*)(&xt[0][0]);
#pragma unroll
        for (int i = 0; i < 8; ++i) dst[tid + 256 * i] = src[tid + 256 * i];
    }
    // weight columns -> registers (L1-cached broadcast across rowgroups)
    float w1c[C_IN];
#pragma unroll
    for (int k = 0; k < C_IN; ++k) w1c[k] = W1[k * HID_ + j];
    float w2a[HID_], w2b[HID_];
#pragma unroll
    for (int k = 0; k < HID_; ++k) {
        w2a[k] = W2[k * G_ + j];
        w2b[k] = W2[k * G_ + j + 32];
    }
    const float bb1 = b1[j];
    const float b2a = b2[j], b2b = b2[j + 32];
    __syncthreads();

    // MLP1: h1 = lrelu(x @ W1 + b1)
#pragma unroll
    for (int r8 = 0; r8 < 8; ++r8) {
        const int r = g * 8 + r8;
        float acc = bb1;
        const float4* xr = (const float4*)(&xt[r][0]);
#pragma unroll
        for (int k4 = 0; k4 < C_IN / 4; ++k4) {
            float4 q = xr[k4];
            acc = fmaf(q.x, w1c[4 * k4 + 0], acc);
            acc = fmaf(q.y, w1c[4 * k4 + 1], acc);
            acc = fmaf(q.z, w1c[4 * k4 + 2], acc);
            acc = fmaf(q.w, w1c[4 * k4 + 3], acc);
        }
        h1t[r][j] = lrelu(acc);
    }
    __syncthreads();

    // MLP2: h2 = lrelu(h1 @ W2 + b2)
#pragma unroll
    for (int r8 = 0; r8 < 8; ++r8) {
        const int r = g * 8 + r8;
        float a0 = b2a, a1 = b2b;
        const float4* hr = (const float4*)(&h1t[r][0]);
#pragma unroll
        for (int k4 = 0; k4 < HID_ / 4; ++k4) {
            float4 q = hr[k4];
            a0 = fmaf(q.x, w2a[4 * k4 + 0], a0);
            a0 = fmaf(q.y, w2a[4 * k4 + 1], a0);
            a0 = fmaf(q.z, w2a[4 * k4 + 2], a0);
            a0 = fmaf(q.w, w2a[4 * k4 + 3], a0);
            a1 = fmaf(q.x, w2b[4 * k4 + 0], a1);
            a1 = fmaf(q.y, w2b[4 * k4 + 1], a1);
            a1 = fmaf(q.z, w2b[4 * k4 + 2], a1);
            a1 = fmaf(q.w, w2b[4 * k4 + 3], a1);
        }
        float* orow = hp + (row0 + r) * G_;
        orow[j]      = lrelu(a0);
        orow[j + 32] = lrelu(a1);
    }
}

// ---------------------------------------------------------------------------
// Kernel B: fused gx + GRU step for one T-chunk.
// grid 256 (1 block/CU), 256 thr = 4 waves, 8 stocks/block (2 per wave).
// lane i owns gate columns {i, i+64, i+128}; all 384 weight floats in VGPRs.
// h state ping-pongs in LDS; carried across launches through d_out.
// ---------------------------------------------------------------------------
__global__ __launch_bounds__(256, 1)
void gru_kernel(const float* __restrict__ hp,    // [TC*S][G_]
                const float* __restrict__ W_ih, const float* __restrict__ W_hh,
                const float* __restrict__ b_ih, const float* __restrict__ b_hh,
                float* __restrict__ hout,        // d_out [S][L_]; h_in when !first
                int first)
{
    __shared__ float wst[192][68];         // padded weight staging (52 KB, reused)
    __shared__ float h2t[8][G_];           // 2 KB
    __shared__ float hbuf[2][8][L_];       // 4 KB ping-pong

    const int tid  = threadIdx.x;
    const int w    = tid >> 6;
    const int lane = tid & 63;
    const int sA   = 2 * w, sB = 2 * w + 1;
    const int s0   = blockIdx.x * 8;

    float4 wih[3][16], whh[3][16];

    // ---- stage W_ih -> LDS (coalesced, padded rows) -> registers ----
    {
        const float4* src = (const float4*)W_ih;
#pragma unroll
        for (int i = 0; i < 12; ++i) {
            int g4 = tid + 256 * i;
            int fw = g4 * 4;
            *(float4*)&wst[fw >> 6][fw & 63] = src[g4];
        }
    }
    __syncthreads();
#pragma unroll
    for (int m = 0; m < 3; ++m) {
        const float4* r = (const float4*)&wst[lane + 64 * m][0];
#pragma unroll
        for (int q = 0; q < 16; ++q) wih[m][q] = r[q];
    }
    __syncthreads();
    // ---- stage W_hh (reuse wst) -> registers ----
    {
        const float4* src = (const float4*)W_hh;
#pragma unroll
        for (int i = 0; i < 12; ++i) {
            int g4 = tid + 256 * i;
            int fw = g4 * 4;
            *(float4*)&wst[fw >> 6][fw & 63] = src[g4];
        }
    }
    __syncthreads();
#pragma unroll
    for (int m = 0; m < 3; ++m) {
        const float4* r = (const float4*)&wst[lane + 64 * m][0];
#pragma unroll
        for (int q = 0; q < 16; ++q) whh[m][q] = r[q];
    }

    float bih[3], bhh[3];
#pragma unroll
    for (int m = 0; m < 3; ++m) {
        bih[m] = b_ih[lane + 64 * m];
        bhh[m] = b_hh[lane + 64 * m];
    }

    // ---- init h state (zero on first chunk, else carried via d_out) ----
    float* hb0 = &hbuf[0][0][0];
    if (first) {
        hb0[2 * tid] = 0.f;
        hb0[2 * tid + 1] = 0.f;
    } else {
        float2 v = *(const float2*)(hout + s0 * L_ + 2 * tid);
        hb0[2 * tid] = v.x;
        hb0[2 * tid + 1] = v.y;
    }
    __syncthreads();

    const float* hpb = hp + (size_t)s0 * G_;
    float2 pf = *(const float2*)(hpb + 2 * tid);   // prefetch t=0 h_proj tile
    int cur = 0;

    for (int t = 0; t < TC; ++t) {
        ((float2*)&h2t[0][0])[tid] = pf;
        __syncthreads();
        if (t + 1 < TC)
            pf = *(const float2*)(hpb + (size_t)(t + 1) * S_TOT * G_ + 2 * tid);

        float axA[3], axB[3], ahA[3], ahB[3];
#pragma unroll
        for (int m = 0; m < 3; ++m) {
            axA[m] = bih[m]; axB[m] = bih[m];
            ahA[m] = bhh[m]; ahB[m] = bhh[m];
        }

        const float4* a4A = (const float4*)&h2t[sA][0];
        const float4* a4B = (const float4*)&h2t[sB][0];
        const float4* h4A = (const float4*)&hbuf[cur][sA][0];
        const float4* h4B = (const float4*)&hbuf[cur][sB][0];
#pragma unroll
        for (int q = 0; q < 16; ++q) {
            float4 aA = a4A[q], aB = a4B[q], hA = h4A[q], hB = h4B[q];
#pragma unroll
            for (int m = 0; m < 3; ++m) {
                float4 wi = wih[m][q], wh = whh[m][q];
                FMA4(axA[m], aA, wi);
                FMA4(axB[m], aB, wi);
                FMA4(ahA[m], hA, wh);
                FMA4(ahB[m], hB, wh);
            }
        }

        // gates: m=0 -> r, m=1 -> z, m=2 -> n  (PyTorch [r,z,n] order)
        float rA = sigf(axA[0] + ahA[0]);
        float zA = sigf(axA[1] + ahA[1]);
        float nA = tanhf_(axA[2] + rA * ahA[2]);
        float rB = sigf(axB[0] + ahB[0]);
        float zB = sigf(axB[1] + ahB[1]);
        float nB = tanhf_(axB[2] + rB * ahB[2]);
        float hnA = (1.f - zA) * nA + zA * hbuf[cur][sA][lane];
        float hnB = (1.f - zB) * nB + zB * hbuf[cur][sB][lane];
        hbuf[cur ^ 1][sA][lane] = hnA;
        hbuf[cur ^ 1][sB][lane] = hnB;
        __syncthreads();
        cur ^= 1;
    }

    const float* hbc = &hbuf[cur][0][0];
    float2 o;
    o.x = hbc[2 * tid];
    o.y = hbc[2 * tid + 1];
    *(float2*)(hout + s0 * L_ + 2 * tid) = o;
}

// ---------------------------------------------------------------------------
extern "C" void kernel_launch(void* const* d_in, const int* in_sizes, int n_in,
                              void* d_out, int out_size, void* d_ws, size_t ws_size,
                              hipStream_t stream)
{
    const float* x    = (const float*)d_in[0];
    const float* W1   = (const float*)d_in[1];
    const float* b1   = (const float*)d_in[2];
    const float* W2   = (const float*)d_in[3];
    const float* b2   = (const float*)d_in[4];
    const float* W_ih = (const float*)d_in[5];
    const float* W_hh = (const float*)d_in[6];
    const float* b_ih = (const float*)d_in[7];
    const float* b_hh = (const float*)d_in[8];
    float* out = (float*)d_out;
    float* hp  = (float*)d_ws;   // TC*S*G floats = 32 MB

    for (int c = 0; c < NCHUNK; ++c) {
        mlp_kernel<<<(TC * S_TOT) / 64, 256, 0, stream>>>(
            x + (size_t)c * TC * S_TOT * C_IN, W1, b1, W2, b2, hp);
        gru_kernel<<<S_TOT / 8, 256, 0, stream>>>(
            hp, W_ih, W_hh, b_ih, b_hh, out, c == 0 ? 1 : 0);
    }
}

// Round 3
// 609.887 us; speedup vs baseline: 3.4573x; 3.4573x over previous
//
#include <hip/hip_runtime.h>
#include <hip/hip_bf16.h>

// Problem dims (fixed by reference)
#define T_TOT 256
#define S_TOT 2048
#define C_IN  128
#define HID_  32
#define G_    64
#define L_    64
// T-chunking: hp fragment buffer in d_ws: TC*128 rowtiles * 4KB = 32 MB (proven-safe ws size)
#define TC    64
#define NCHUNK (T_TOT / TC)

typedef __attribute__((ext_vector_type(8))) short short8;
typedef __attribute__((ext_vector_type(4))) float f32x4;

#define MFMA(a, b, c) __builtin_amdgcn_mfma_f32_16x16x32_bf16((a), (b), (c), 0, 0, 0)

// fp32 -> bf16 split: v ~= hi + lo with residual ~2^-18 * |v|
__device__ __forceinline__ void fsplit(float v, ushort& hi, ushort& lo) {
    __hip_bfloat16 h = __float2bfloat16(v);
    float hf = __bfloat162float(h);
    __hip_bfloat16 l = __float2bfloat16(v - hf);
    hi = *reinterpret_cast<ushort*>(&h);
    lo = *reinterpret_cast<ushort*>(&l);
}

__device__ __forceinline__ float lrelu(float v) { return v >= 0.f ? v : 0.01f * v; }

__device__ __forceinline__ float sig1(float x) {
    x = fminf(fmaxf(x, -30.f), 30.f);
    return __builtin_amdgcn_rcpf(1.f + __expf(-x));
}
__device__ __forceinline__ float th1(float x) {
    x = fminf(fmaxf(x, -15.f), 15.f);
    float e = __expf(-2.f * x);
    return (1.f - e) * __builtin_amdgcn_rcpf(1.f + e);
}

// ---------------------------------------------------------------------------
// Kernel A: x -> MLP1 -> MLP2 -> h_proj, all MFMA (split-bf16).
// 256 thr = 4 waves; wave w owns 16 rows (one 16x16x32 M-tile) end-to-end.
// Output: hp fragments (bf16 hi/lo planes) in A-frag order:
//   float4 ws[((rt*2 + ks)*2 + pl)*64 + lane], rt = row/16 = t_local*128 + s16
// All LDS bf16 planes XOR-swizzled: byte ^= (row & MASK) << 4 (bank conflicts).
// ---------------------------------------------------------------------------
__global__ __launch_bounds__(256, 2)
void mlp_kernel(const float* __restrict__ x,   // chunk base
                const float* __restrict__ W1, const float* __restrict__ b1,
                const float* __restrict__ W2, const float* __restrict__ b2,
                float* __restrict__ hpws)
{
    __shared__ ushort w1h[32][128], w1l[32][128];   // W1^T [n][k], 16 KB
    __shared__ ushort w2h[64][32],  w2l[64][32];    // W2^T [n][k],  8 KB
    __shared__ ushort xh[4][16][128], xl[4][16][128];  // x tiles, 32 KB (reused for hp)
    __shared__ ushort h1h[4][16][32], h1l[4][16][32];  // h1 tiles,  8 KB

    const int tid = threadIdx.x;
    const int w = tid >> 6, l = tid & 63;
    const int lg = l >> 4, lr = l & 15;

    // ---- stage W1 (global [k=128][n=32]) -> transposed swizzled planes ----
#pragma unroll
    for (int i = 0; i < 16; ++i) {
        int e = tid + 256 * i;
        int k = e >> 5, n = e & 31;
        ushort hi, lo; fsplit(W1[e], hi, lo);
        int by = (2 * k) ^ ((n & 7) << 4);
        *(ushort*)((char*)&w1h[n][0] + by) = hi;
        *(ushort*)((char*)&w1l[n][0] + by) = lo;
    }
    // ---- stage W2 (global [k=32][n=64]) ----
#pragma unroll
    for (int i = 0; i < 8; ++i) {
        int e = tid + 256 * i;
        int k = e >> 6, n = e & 63;
        ushort hi, lo; fsplit(W2[e], hi, lo);
        int by = (2 * k) ^ ((n & 3) << 4);
        *(ushort*)((char*)&w2h[n][0] + by) = hi;
        *(ushort*)((char*)&w2l[n][0] + by) = lo;
    }

    // ---- stage x: 16 rows per wave, split to bf16 planes ----
    const size_t row0 = (size_t)blockIdx.x * 64 + w * 16;
    const float4* xg = (const float4*)(x + row0 * C_IN);
#pragma unroll
    for (int i = 0; i < 8; ++i) {
        int f4 = l + 64 * i;
        int r = f4 >> 5, c4 = f4 & 31;
        float4 v = xg[f4];
        ushort h4[4], l4[4];
        fsplit(v.x, h4[0], l4[0]);
        fsplit(v.y, h4[1], l4[1]);
        fsplit(v.z, h4[2], l4[2]);
        fsplit(v.w, h4[3], l4[3]);
        int by = (8 * c4) ^ ((r & 7) << 4);
        ushort4 ph = {h4[0], h4[1], h4[2], h4[3]};
        ushort4 pl = {l4[0], l4[1], l4[2], l4[3]};
        *(ushort4*)((char*)&xh[w][r][0] + by) = ph;
        *(ushort4*)((char*)&xl[w][r][0] + by) = pl;
    }
    __syncthreads();

    // ---- MLP1: h1 = lrelu(x @ W1 + b1), M=16 N=32 K=128 ----
    f32x4 h1acc[2];
#pragma unroll
    for (int nt = 0; nt < 2; ++nt) {
        int col = lr + 16 * nt;
        float bb = b1[col];
        f32x4 acc = {bb, bb, bb, bb};
#pragma unroll
        for (int ks = 0; ks < 4; ++ks) {
            int aby = (64 * ks + 16 * lg) ^ ((lr & 7) << 4);
            short8 ahi = *(short8*)((char*)&xh[w][lr][0] + aby);
            short8 alo = *(short8*)((char*)&xl[w][lr][0] + aby);
            int bby = (64 * ks + 16 * lg) ^ ((col & 7) << 4);
            short8 bhi = *(short8*)((char*)&w1h[col][0] + bby);
            short8 blo = *(short8*)((char*)&w1l[col][0] + bby);
            acc = MFMA(ahi, bhi, acc);
            acc = MFMA(ahi, blo, acc);
            acc = MFMA(alo, bhi, acc);
        }
        h1acc[nt] = acc;
    }
    // write h1 planes (C/D layout: row = 4*lg + r, col = lr + 16*nt)
#pragma unroll
    for (int nt = 0; nt < 2; ++nt) {
        int col = lr + 16 * nt;
#pragma unroll
        for (int r = 0; r < 4; ++r) {
            float v = lrelu(h1acc[nt][r]);
            ushort hi, lo; fsplit(v, hi, lo);
            int row = 4 * lg + r;
            int by = (2 * col) ^ ((row & 3) << 4);
            *(ushort*)((char*)&h1h[w][row][0] + by) = hi;
            *(ushort*)((char*)&h1l[w][row][0] + by) = lo;
        }
    }
    __syncthreads();

    // ---- MLP2: hp = lrelu(h1 @ W2 + b2), M=16 N=64 K=32 ----
    f32x4 hpacc[4];
#pragma unroll
    for (int nt = 0; nt < 4; ++nt) {
        int col = lr + 16 * nt;
        float bb = b2[col];
        f32x4 acc = {bb, bb, bb, bb};
        int aby = (16 * lg) ^ ((lr & 3) << 4);
        short8 ahi = *(short8*)((char*)&h1h[w][lr][0] + aby);
        short8 alo = *(short8*)((char*)&h1l[w][lr][0] + aby);
        int bby = (16 * lg) ^ ((col & 3) << 4);
        short8 bhi = *(short8*)((char*)&w2h[col][0] + bby);
        short8 blo = *(short8*)((char*)&w2l[col][0] + bby);
        acc = MFMA(ahi, bhi, acc);
        acc = MFMA(ahi, blo, acc);
        acc = MFMA(alo, bhi, acc);
        hpacc[nt] = acc;
    }
    __syncthreads();
    // write hp into reused x planes ([16][128] layout, cols 0..63)
#pragma unroll
    for (int nt = 0; nt < 4; ++nt) {
        int col = lr + 16 * nt;
#pragma unroll
        for (int r = 0; r < 4; ++r) {
            float v = lrelu(hpacc[nt][r]);
            ushort hi, lo; fsplit(v, hi, lo);
            int row = 4 * lg + r;
            int by = (2 * col) ^ ((row & 7) << 4);
            *(ushort*)((char*)&xh[w][row][0] + by) = hi;
            *(ushort*)((char*)&xl[w][row][0] + by) = lo;
        }
    }
    __syncthreads();

    // ---- export hp as A-fragments (coalesced float4 stores) ----
    const size_t rt = row0 >> 4;          // t_local*128 + s16
    float4* outw = (float4*)hpws;
#pragma unroll
    for (int ks = 0; ks < 2; ++ks) {
        int by = (64 * ks + 16 * lg) ^ ((lr & 7) << 4);
        short8 fh = *(short8*)((char*)&xh[w][lr][0] + by);
        short8 fl = *(short8*)((char*)&xl[w][lr][0] + by);
        outw[((rt * 2 + ks) * 2 + 0) * 64 + l] = *(float4*)&fh;
        outw[((rt * 2 + ks) * 2 + 1) * 64 + l] = *(float4*)&fl;
    }
}

// ---------------------------------------------------------------------------
// Kernel B: GRU recurrence, MFMA. 128 blocks x 16 stocks, 4 waves.
// Wave w owns gate-col-tiles {w, w+4, w+8} -> cols {c, c+64, c+128}, c=16w+lr:
// r/z/n for a column live in the same lane (C/D layout). W_ih/W_hh B-frags
// persist in VGPRs (~96). h state: swizzled bf16 hi/lo LDS planes [16][64].
// h carried across chunk launches through d_out.
// ---------------------------------------------------------------------------
__global__ __launch_bounds__(256, 1)
void gru_kernel(const float* __restrict__ hpws_f,
                const float* __restrict__ W_ih, const float* __restrict__ W_hh,
                const float* __restrict__ b_ih, const float* __restrict__ b_hh,
                float* __restrict__ out, int first)
{
    __shared__ ushort hh_[16][64], hl_[16][64];   // h planes, 4 KB

    const int tid = threadIdx.x;
    const int w = tid >> 6, l = tid & 63;
    const int lg = l >> 4, lr = l & 15;
    const int colr = 16 * w + lr;        // latent col (0..63)
    const int b = blockIdx.x;            // stock tile (16 stocks)

    // ---- persistent B-fragments: W_ih / W_hh rows are contiguous in k ----
    short8 wih_h[3][2], wih_l[3][2], whh_h[3][2], whh_l[3][2];
    float bih[3], bhh[3];
#pragma unroll
    for (int g = 0; g < 3; ++g) {
        int n = colr + 64 * g;
        bih[g] = b_ih[n];
        bhh[g] = b_hh[n];
#pragma unroll
        for (int ks = 0; ks < 2; ++ks) {
            const float* p = W_ih + n * 64 + 32 * ks + 8 * lg;
            const float* q = W_hh + n * 64 + 32 * ks + 8 * lg;
            short8 ph, pl, qh, ql;
#pragma unroll
            for (int j = 0; j < 8; ++j) {
                ushort hi, lo;
                fsplit(p[j], hi, lo); ph[j] = (short)hi; pl[j] = (short)lo;
                fsplit(q[j], hi, lo); qh[j] = (short)hi; ql[j] = (short)lo;
            }
            wih_h[g][ks] = ph; wih_l[g][ks] = pl;
            whh_h[g][ks] = qh; whh_l[g][ks] = ql;
        }
    }

    // ---- init h (zero on first chunk, else carried via d_out) ----
    f32x4 hprev;
#pragma unroll
    for (int r = 0; r < 4; ++r) {
        int s = 16 * b + 4 * lg + r;
        hprev[r] = first ? 0.f : out[s * 64 + colr];
    }
#pragma unroll
    for (int r = 0; r < 4; ++r) {
        ushort hi, lo; fsplit(hprev[r], hi, lo);
        int row = 4 * lg + r;
        int by = (2 * colr) ^ ((row & 7) << 4);
        *(ushort*)((char*)&hh_[row][0] + by) = hi;
        *(ushort*)((char*)&hl_[row][0] + by) = lo;
    }
    __syncthreads();

    const short8* hpg = (const short8*)hpws_f;
    short8 cur[2][2], nxt[2][2];
    {
        size_t rt = (size_t)b;   // t=0
#pragma unroll
        for (int ks = 0; ks < 2; ++ks)
#pragma unroll
            for (int pl = 0; pl < 2; ++pl)
                cur[ks][pl] = hpg[((rt * 2 + ks) * 2 + pl) * 64 + l];
    }

    for (int t = 0; t < TC; ++t) {
        if (t + 1 < TC) {
            size_t rt = (size_t)(t + 1) * 128 + b;
#pragma unroll
            for (int ks = 0; ks < 2; ++ks)
#pragma unroll
                for (int pl = 0; pl < 2; ++pl)
                    nxt[ks][pl] = hpg[((rt * 2 + ks) * 2 + pl) * 64 + l];
        }

        // gx = hp @ W_ih^T + b_ih  (per-wave: its 3 gate col-tiles)
        f32x4 agx[3], agh[3];
#pragma unroll
        for (int g = 0; g < 3; ++g) {
            float bb = bih[g];
            agx[g] = {bb, bb, bb, bb};
        }
#pragma unroll
        for (int ks = 0; ks < 2; ++ks)
#pragma unroll
            for (int g = 0; g < 3; ++g) {
                agx[g] = MFMA(cur[ks][0], wih_h[g][ks], agx[g]);
                agx[g] = MFMA(cur[ks][0], wih_l[g][ks], agx[g]);
                agx[g] = MFMA(cur[ks][1], wih_h[g][ks], agx[g]);
            }

        // gh = h @ W_hh^T + b_hh
        short8 ah[2], al[2];
#pragma unroll
        for (int ks = 0; ks < 2; ++ks) {
            int by = (64 * ks + 16 * lg) ^ ((lr & 7) << 4);
            ah[ks] = *(short8*)((char*)&hh_[lr][0] + by);
            al[ks] = *(short8*)((char*)&hl_[lr][0] + by);
        }
#pragma unroll
        for (int g = 0; g < 3; ++g) {
            float bb = bhh[g];
            agh[g] = {bb, bb, bb, bb};
        }
#pragma unroll
        for (int ks = 0; ks < 2; ++ks)
#pragma unroll
            for (int g = 0; g < 3; ++g) {
                agh[g] = MFMA(ah[ks], whh_h[g][ks], agh[g]);
                agh[g] = MFMA(ah[ks], whh_l[g][ks], agh[g]);
                agh[g] = MFMA(al[ks], whh_h[g][ks], agh[g]);
            }

        // gates (lane-local): g0=r, g1=z, g2=n
        f32x4 hn;
#pragma unroll
        for (int r = 0; r < 4; ++r) {
            float rr = sig1(agx[0][r] + agh[0][r]);
            float zz = sig1(agx[1][r] + agh[1][r]);
            float nn = th1(agx[2][r] + rr * agh[2][r]);
            hn[r] = (1.f - zz) * nn + zz * hprev[r];
        }

        __syncthreads();   // all waves done reading h planes
#pragma unroll
        for (int r = 0; r < 4; ++r) {
            ushort hi, lo; fsplit(hn[r], hi, lo);
            int row = 4 * lg + r;
            int by = (2 * colr) ^ ((row & 7) << 4);
            *(ushort*)((char*)&hh_[row][0] + by) = hi;
            *(ushort*)((char*)&hl_[row][0] + by) = lo;
        }
        hprev = hn;
        __syncthreads();   // new h visible

#pragma unroll
        for (int ks = 0; ks < 2; ++ks)
#pragma unroll
            for (int pl = 0; pl < 2; ++pl)
                cur[ks][pl] = nxt[ks][pl];
    }

#pragma unroll
    for (int r = 0; r < 4; ++r)
        out[(16 * b + 4 * lg + r) * 64 + colr] = hprev[r];
}

// ---------------------------------------------------------------------------
extern "C" void kernel_launch(void* const* d_in, const int* in_sizes, int n_in,
                              void* d_out, int out_size, void* d_ws, size_t ws_size,
                              hipStream_t stream)
{
    const float* x    = (const float*)d_in[0];
    const float* W1   = (const float*)d_in[1];
    const float* b1   = (const float*)d_in[2];
    const float* W2   = (const float*)d_in[3];
    const float* b2   = (const float*)d_in[4];
    const float* W_ih = (const float*)d_in[5];
    const float* W_hh = (const float*)d_in[6];
    const float* b_ih = (const float*)d_in[7];
    const float* b_hh = (const float*)d_in[8];
    float* out  = (float*)d_out;
    float* hpws = (float*)d_ws;   // TC*128 rowtiles * 4 KB = 32 MB

    for (int c = 0; c < NCHUNK; ++c) {
        mlp_kernel<<<(TC * S_TOT) / 64, 256, 0, stream>>>(
            x + (size_t)c * TC * S_TOT * C_IN, W1, b1, W2, b2, hpws);
        gru_kernel<<<S_TOT / 16, 256, 0, stream>>>(
            hpws, W_ih, W_hh, b_ih, b_hh, out, c == 0 ? 1 : 0);
    }
}

// Round 5
// 606.092 us; speedup vs baseline: 3.4789x; 1.0063x over previous
//
#include <hip/hip_runtime.h>
#include <hip/hip_bf16.h>

// Problem dims (fixed by reference)
#define T_TOT 256
#define S_TOT 2048
#define C_IN  128
#define HID_  32
#define G_    64
#define L_    64

typedef __attribute__((ext_vector_type(8))) short short8;
typedef __attribute__((ext_vector_type(4))) float f32x4;

#define MFMA(a, b, c) __builtin_amdgcn_mfma_f32_16x16x32_bf16((a), (b), (c), 0, 0, 0)

// fp32 -> bf16 split: v ~= hi + lo with residual ~2^-18 * |v|
__device__ __forceinline__ void fsplit(float v, ushort& hi, ushort& lo) {
    __hip_bfloat16 h = __float2bfloat16(v);
    float hf = __bfloat162float(h);
    __hip_bfloat16 l = __float2bfloat16(v - hf);
    hi = *reinterpret_cast<ushort*>(&h);
    lo = *reinterpret_cast<ushort*>(&l);
}

__device__ __forceinline__ float lrelu(float v) { return v >= 0.f ? v : 0.01f * v; }

__device__ __forceinline__ float sig1(float x) {
    x = fminf(fmaxf(x, -30.f), 30.f);
    return __builtin_amdgcn_rcpf(1.f + __expf(-x));
}
__device__ __forceinline__ float th1(float x) {
    x = fminf(fmaxf(x, -15.f), 15.f);
    float e = __expf(-2.f * x);
    return (1.f - e) * __builtin_amdgcn_rcpf(1.f + e);
}

// ---------------------------------------------------------------------------
// Kernel A: x -> MLP1 -> MLP2 -> h_proj, all MFMA (split-bf16). One launch,
// grid = T*S/64 blocks. Wave w owns 16 rows end-to-end. Output: hp fragments
// (bf16 hi/lo planes) in A-frag order:
//   float4 ws[((rt*2 + ks)*2 + pl)*64 + lane], rt = row/16 = t*128 + s16
// All LDS bf16 planes XOR-swizzled: byte ^= (row & MASK) << 4.
// ---------------------------------------------------------------------------
__global__ __launch_bounds__(256, 2)
void mlp_kernel(const float* __restrict__ x,
                const float* __restrict__ W1, const float* __restrict__ b1,
                const float* __restrict__ W2, const float* __restrict__ b2,
                float* __restrict__ hpws)
{
    __shared__ ushort w1h[32][128], w1l[32][128];      // W1^T [n][k], 16 KB
    __shared__ ushort w2h[64][32],  w2l[64][32];       // W2^T [n][k],  8 KB
    __shared__ ushort xh[4][16][128], xl[4][16][128];  // x tiles, 32 KB (reused for hp)
    __shared__ ushort h1h[4][16][32], h1l[4][16][32];  // h1 tiles,  8 KB

    const int tid = threadIdx.x;
    const int w = tid >> 6, l = tid & 63;
    const int lg = l >> 4, lr = l & 15;

    // ---- stage W1 (global [k=128][n=32]) -> transposed swizzled planes ----
#pragma unroll
    for (int i = 0; i < 16; ++i) {
        int e = tid + 256 * i;
        int k = e >> 5, n = e & 31;
        ushort hi, lo; fsplit(W1[e], hi, lo);
        int by = (2 * k) ^ ((n & 7) << 4);
        *(ushort*)((char*)&w1h[n][0] + by) = hi;
        *(ushort*)((char*)&w1l[n][0] + by) = lo;
    }
    // ---- stage W2 (global [k=32][n=64]) ----
#pragma unroll
    for (int i = 0; i < 8; ++i) {
        int e = tid + 256 * i;
        int k = e >> 6, n = e & 63;
        ushort hi, lo; fsplit(W2[e], hi, lo);
        int by = (2 * k) ^ ((n & 3) << 4);
        *(ushort*)((char*)&w2h[n][0] + by) = hi;
        *(ushort*)((char*)&w2l[n][0] + by) = lo;
    }

    // ---- stage x: 16 rows per wave, split to bf16 planes ----
    const size_t row0 = (size_t)blockIdx.x * 64 + w * 16;
    const float4* xg = (const float4*)(x + row0 * C_IN);
#pragma unroll
    for (int i = 0; i < 8; ++i) {
        int f4 = l + 64 * i;
        int r = f4 >> 5, c4 = f4 & 31;
        float4 v = xg[f4];
        ushort h4[4], l4[4];
        fsplit(v.x, h4[0], l4[0]);
        fsplit(v.y, h4[1], l4[1]);
        fsplit(v.z, h4[2], l4[2]);
        fsplit(v.w, h4[3], l4[3]);
        int by = (8 * c4) ^ ((r & 7) << 4);
        ushort4 ph = {h4[0], h4[1], h4[2], h4[3]};
        ushort4 pl = {l4[0], l4[1], l4[2], l4[3]};
        *(ushort4*)((char*)&xh[w][r][0] + by) = ph;
        *(ushort4*)((char*)&xl[w][r][0] + by) = pl;
    }
    __syncthreads();

    // ---- MLP1: h1 = lrelu(x @ W1 + b1), M=16 N=32 K=128 ----
    f32x4 h1acc[2];
#pragma unroll
    for (int nt = 0; nt < 2; ++nt) {
        int col = lr + 16 * nt;
        float bb = b1[col];
        f32x4 acc = {bb, bb, bb, bb};
#pragma unroll
        for (int ks = 0; ks < 4; ++ks) {
            int aby = (64 * ks + 16 * lg) ^ ((lr & 7) << 4);
            short8 ahi = *(short8*)((char*)&xh[w][lr][0] + aby);
            short8 alo = *(short8*)((char*)&xl[w][lr][0] + aby);
            int bby = (64 * ks + 16 * lg) ^ ((col & 7) << 4);
            short8 bhi = *(short8*)((char*)&w1h[col][0] + bby);
            short8 blo = *(short8*)((char*)&w1l[col][0] + bby);
            acc = MFMA(ahi, bhi, acc);
            acc = MFMA(ahi, blo, acc);
            acc = MFMA(alo, bhi, acc);
        }
        h1acc[nt] = acc;
    }
    // write h1 planes (C/D layout: row = 4*lg + r, col = lr + 16*nt)
#pragma unroll
    for (int nt = 0; nt < 2; ++nt) {
        int col = lr + 16 * nt;
#pragma unroll
        for (int r = 0; r < 4; ++r) {
            float v = lrelu(h1acc[nt][r]);
            ushort hi, lo; fsplit(v, hi, lo);
            int row = 4 * lg + r;
            int by = (2 * col) ^ ((row & 3) << 4);
            *(ushort*)((char*)&h1h[w][row][0] + by) = hi;
            *(ushort*)((char*)&h1l[w][row][0] + by) = lo;
        }
    }
    __syncthreads();

    // ---- MLP2: hp = lrelu(h1 @ W2 + b2), M=16 N=64 K=32 ----
    f32x4 hpacc[4];
#pragma unroll
    for (int nt = 0; nt < 4; ++nt) {
        int col = lr + 16 * nt;
        float bb = b2[col];
        f32x4 acc = {bb, bb, bb, bb};
        int aby = (16 * lg) ^ ((lr & 3) << 4);
        short8 ahi = *(short8*)((char*)&h1h[w][lr][0] + aby);
        short8 alo = *(short8*)((char*)&h1l[w][lr][0] + aby);
        int bby = (16 * lg) ^ ((col & 3) << 4);
        short8 bhi = *(short8*)((char*)&w2h[col][0] + bby);
        short8 blo = *(short8*)((char*)&w2l[col][0] + bby);
        acc = MFMA(ahi, bhi, acc);
        acc = MFMA(ahi, blo, acc);
        acc = MFMA(alo, bhi, acc);
        hpacc[nt] = acc;
    }
    __syncthreads();
    // write hp into reused x planes ([16][128] layout, cols 0..63)
#pragma unroll
    for (int nt = 0; nt < 4; ++nt) {
        int col = lr + 16 * nt;
#pragma unroll
        for (int r = 0; r < 4; ++r) {
            float v = lrelu(hpacc[nt][r]);
            ushort hi, lo; fsplit(v, hi, lo);
            int row = 4 * lg + r;
            int by = (2 * col) ^ ((row & 7) << 4);
            *(ushort*)((char*)&xh[w][row][0] + by) = hi;
            *(ushort*)((char*)&xl[w][row][0] + by) = lo;
        }
    }
    __syncthreads();

    // ---- export hp as A-fragments (coalesced float4 stores) ----
    const size_t rt = row0 >> 4;          // t*128 + s16
    float4* outw = (float4*)hpws;
#pragma unroll
    for (int ks = 0; ks < 2; ++ks) {
        int by = (64 * ks + 16 * lg) ^ ((lr & 7) << 4);
        short8 fh = *(short8*)((char*)&xh[w][lr][0] + by);
        short8 fl = *(short8*)((char*)&xl[w][lr][0] + by);
        outw[((rt * 2 + ks) * 2 + 0) * 64 + l] = *(float4*)&fh;
        outw[((rt * 2 + ks) * 2 + 1) * 64 + l] = *(float4*)&fl;
    }
}

// ---------------------------------------------------------------------------
// Kernel B: GRU, single launch over all 256 steps. 128 blocks x 16 stocks,
// 4 waves. Wave w owns gate-col-tiles {w, w+4, w+8}; r/z/n for a column live
// in the same lane. Per step: ONE raw barrier (ping-pong h LDS planes,
// lgkmcnt(0)-only drain — global prefetch loads stay in flight across it),
// 3-slot static prefetch ring (2 steps deep), depth-2 MFMA chains.
// ---------------------------------------------------------------------------
__device__ __forceinline__ void gstep(
    const short8 (&cur)[2][2], short8 (&pf)[2][2], int t,
    const short8* __restrict__ hpg, int b, int l, int lg, int lr, int colr,
    const short8 (&wih_h)[3][2], const short8 (&wih_l)[3][2],
    const short8 (&whh_h)[3][2], const short8 (&whh_l)[3][2],
    const float (&bih)[3], const float (&bhh)[3],
    f32x4& hprev, int& p, ushort* hbh, ushort* hbl)
{
    // prefetch t+2 into pf (stays in flight across the barrier below)
    if (t + 2 < T_TOT) {
        size_t rt = (size_t)(t + 2) * 128 + b;
#pragma unroll
        for (int ks = 0; ks < 2; ++ks)
#pragma unroll
            for (int pl = 0; pl < 2; ++pl)
                pf[ks][pl] = hpg[((rt * 2 + ks) * 2 + pl) * 64 + l];
    }

    // read h A-fragments from buf[p]
    const ushort* rh = hbh + p * 1024;
    const ushort* rl = hbl + p * 1024;
    short8 ah[2], al[2];
#pragma unroll
    for (int ks = 0; ks < 2; ++ks) {
        int by = (64 * ks + 16 * lg) ^ ((lr & 7) << 4);
        ah[ks] = *(short8*)((char*)(rh + lr * 64) + by);
        al[ks] = *(short8*)((char*)(rl + lr * 64) + by);
    }

    // gx = hp @ W_ih^T + b_ih : 3 independent depth-2 chains per gate
    f32x4 agx[3], agh[3];
#pragma unroll
    for (int g = 0; g < 3; ++g) {
        f32x4 c0 = {bih[g], bih[g], bih[g], bih[g]};
        f32x4 c1 = {0.f, 0.f, 0.f, 0.f};
        f32x4 c2 = {0.f, 0.f, 0.f, 0.f};
        c0 = MFMA(cur[0][0], wih_h[g][0], c0);
        c1 = MFMA(cur[0][0], wih_l[g][0], c1);
        c2 = MFMA(cur[0][1], wih_h[g][0], c2);
        c0 = MFMA(cur[1][0], wih_h[g][1], c0);
        c1 = MFMA(cur[1][0], wih_l[g][1], c1);
        c2 = MFMA(cur[1][1], wih_h[g][1], c2);
        agx[g] = c0 + c1 + c2;
    }
    // gh = h @ W_hh^T + b_hh
#pragma unroll
    for (int g = 0; g < 3; ++g) {
        f32x4 c0 = {bhh[g], bhh[g], bhh[g], bhh[g]};
        f32x4 c1 = {0.f, 0.f, 0.f, 0.f};
        f32x4 c2 = {0.f, 0.f, 0.f, 0.f};
        c0 = MFMA(ah[0], whh_h[g][0], c0);
        c1 = MFMA(ah[0], whh_l[g][0], c1);
        c2 = MFMA(al[0], whh_h[g][0], c2);
        c0 = MFMA(ah[1], whh_h[g][1], c0);
        c1 = MFMA(ah[1], whh_l[g][1], c1);
        c2 = MFMA(al[1], whh_h[g][1], c2);
        agh[g] = c0 + c1 + c2;
    }

    // gates: g0=r, g1=z, g2=n (lane-local triples)
    f32x4 hn;
#pragma unroll
    for (int r = 0; r < 4; ++r) {
        float rr = sig1(agx[0][r] + agh[0][r]);
        float zz = sig1(agx[1][r] + agh[1][r]);
        float nn = th1(agx[2][r] + rr * agh[2][r]);
        hn[r] = (1.f - zz) * nn + zz * hprev[r];
    }

    // write h_new -> buf[p^1]
    ushort* wh = hbh + (p ^ 1) * 1024;
    ushort* wl = hbl + (p ^ 1) * 1024;
#pragma unroll
    for (int r = 0; r < 4; ++r) {
        ushort hi, lo; fsplit(hn[r], hi, lo);
        int row = 4 * lg + r;
        int by = (2 * colr) ^ ((row & 7) << 4);
        *(ushort*)((char*)(wh + row * 64) + by) = hi;
        *(ushort*)((char*)(wl + row * 64) + by) = lo;
    }
    hprev = hn;

    // LDS-only drain + raw barrier: vmcnt (prefetch) NOT drained
    asm volatile("s_waitcnt lgkmcnt(0)\n\ts_barrier" ::: "memory");
    p ^= 1;
}

__global__ __launch_bounds__(256, 1)
void gru_kernel(const float* __restrict__ hpws_f,
                const float* __restrict__ W_ih, const float* __restrict__ W_hh,
                const float* __restrict__ b_ih, const float* __restrict__ b_hh,
                float* __restrict__ out)
{
    __shared__ ushort hbh_s[2][16][64], hbl_s[2][16][64];   // ping-pong h planes, 8 KB

    const int tid = threadIdx.x;
    const int w = tid >> 6, l = tid & 63;
    const int lg = l >> 4, lr = l & 15;
    const int colr = 16 * w + lr;        // latent col (0..63)
    const int b = blockIdx.x;            // stock tile (16 stocks)
    ushort* hbh = &hbh_s[0][0][0];
    ushort* hbl = &hbl_s[0][0][0];

    // ---- persistent B-fragments (W rows contiguous in k) ----
    short8 wih_h[3][2], wih_l[3][2], whh_h[3][2], whh_l[3][2];
    float bih[3], bhh[3];
#pragma unroll
    for (int g = 0; g < 3; ++g) {
        int n = colr + 64 * g;
        bih[g] = b_ih[n];
        bhh[g] = b_hh[n];
#pragma unroll
        for (int ks = 0; ks < 2; ++ks) {
            const float* pp = W_ih + n * 64 + 32 * ks + 8 * lg;
            const float* qq = W_hh + n * 64 + 32 * ks + 8 * lg;
            short8 ph, pl, qh, ql;
#pragma unroll
            for (int j = 0; j < 8; ++j) {
                ushort hi, lo;
                fsplit(pp[j], hi, lo); ph[j] = (short)hi; pl[j] = (short)lo;
                fsplit(qq[j], hi, lo); qh[j] = (short)hi; ql[j] = (short)lo;
            }
            wih_h[g][ks] = ph; wih_l[g][ks] = pl;
            whh_h[g][ks] = qh; whh_l[g][ks] = ql;
        }
    }

    // ---- h0 = 0 ----
    f32x4 hprev = {0.f, 0.f, 0.f, 0.f};
#pragma unroll
    for (int r = 0; r < 4; ++r) {
        int row = 4 * lg + r;
        int by = (2 * colr) ^ ((row & 7) << 4);
        *(ushort*)((char*)(hbh + row * 64) + by) = 0;
        *(ushort*)((char*)(hbl + row * 64) + by) = 0;
    }
    asm volatile("s_waitcnt lgkmcnt(0)\n\ts_barrier" ::: "memory");
    int p = 0;

    // ---- prefetch ring prologue: t=0 -> ring[0], t=1 -> ring[1] ----
    const short8* hpg = (const short8*)hpws_f;
    short8 ring[3][2][2];
#pragma unroll
    for (int tt = 0; tt < 2; ++tt) {
        size_t rt = (size_t)tt * 128 + b;
#pragma unroll
        for (int ks = 0; ks < 2; ++ks)
#pragma unroll
            for (int pl = 0; pl < 2; ++pl)
                ring[tt][ks][pl] = hpg[((rt * 2 + ks) * 2 + pl) * 64 + l];
    }

    // ---- main loop: 85 x 3 steps (t = 0..254), static ring indices ----
    for (int tb = 0; tb < 255; tb += 3) {
        gstep(ring[0], ring[2], tb + 0, hpg, b, l, lg, lr, colr,
              wih_h, wih_l, whh_h, whh_l, bih, bhh, hprev, p, hbh, hbl);
        gstep(ring[1], ring[0], tb + 1, hpg, b, l, lg, lr, colr,
              wih_h, wih_l, whh_h, whh_l, bih, bhh, hprev, p, hbh, hbl);
        gstep(ring[2], ring[1], tb + 2, hpg, b, l, lg, lr, colr,
              wih_h, wih_l, whh_h, whh_l, bih, bhh, hprev, p, hbh, hbl);
    }
    // epilogue: t = 255 (255 % 3 == 0 -> ring[0]; no prefetch, guard blocks it)
    gstep(ring[0], ring[2], 255, hpg, b, l, lg, lr, colr,
          wih_h, wih_l, whh_h, whh_l, bih, bhh, hprev, p, hbh, hbl);

#pragma unroll
    for (int r = 0; r < 4; ++r)
        out[(16 * b + 4 * lg + r) * 64 + colr] = hprev[r];
}

// ---------------------------------------------------------------------------
extern "C" void kernel_launch(void* const* d_in, const int* in_sizes, int n_in,
                              void* d_out, int out_size, void* d_ws, size_t ws_size,
                              hipStream_t stream)
{
    const float* x    = (const float*)d_in[0];
    const float* W1   = (const float*)d_in[1];
    const float* b1   = (const float*)d_in[2];
    const float* W2   = (const float*)d_in[3];
    const float* b2   = (const float*)d_in[4];
    const float* W_ih = (const float*)d_in[5];
    const float* W_hh = (const float*)d_in[6];
    const float* b_ih = (const float*)d_in[7];
    const float* b_hh = (const float*)d_in[8];
    float* out  = (float*)d_out;
    float* hpws = (float*)d_ws;   // T*S/16 rowtiles * 4 KB = 128 MB (ws ~1 GB)

    mlp_kernel<<<(T_TOT * S_TOT) / 64, 256, 0, stream>>>(x, W1, b1, W2, b2, hpws);
    gru_kernel<<<S_TOT / 16, 256, 0, stream>>>(hpws, W_ih, W_hh, b_ih, b_hh, out);
}

// Round 6
// 595.334 us; speedup vs baseline: 3.5418x; 1.0181x over previous
//
#include <hip/hip_runtime.h>
#include <hip/hip_bf16.h>

// Problem dims (fixed by reference)
#define T_TOT 256
#define S_TOT 2048
#define C_IN  128
#define HID_  32
#define G_    64
#define L_    64

typedef __attribute__((ext_vector_type(8))) short short8;
typedef __attribute__((ext_vector_type(4))) float f32x4;

#define MFMA(a, b, c) __builtin_amdgcn_mfma_f32_16x16x32_bf16((a), (b), (c), 0, 0, 0)

// fp32 -> bf16 split: v ~= hi + lo with residual ~2^-18 * |v|
__device__ __forceinline__ void fsplit(float v, ushort& hi, ushort& lo) {
    __hip_bfloat16 h = __float2bfloat16(v);
    float hf = __bfloat162float(h);
    __hip_bfloat16 l = __float2bfloat16(v - hf);
    hi = *reinterpret_cast<ushort*>(&h);
    lo = *reinterpret_cast<ushort*>(&l);
}

__device__ __forceinline__ float lrelu(float v) { return v >= 0.f ? v : 0.01f * v; }

__device__ __forceinline__ float sig1(float x) {
    x = fminf(fmaxf(x, -30.f), 30.f);
    return __builtin_amdgcn_rcpf(1.f + __expf(-x));
}
__device__ __forceinline__ float th1(float x) {
    x = fminf(fmaxf(x, -15.f), 15.f);
    float e = __expf(-2.f * x);
    return (1.f - e) * __builtin_amdgcn_rcpf(1.f + e);
}

// ---------------------------------------------------------------------------
// Setup kernel (1 block): pre-split W1/W2 into bf16 hi/lo B-fragment layout.
//   w1f[((nt*4+ks)*2+pl)*64 + l]  (nt<2, ks<4): lane l holds W1[32ks+8lg+j][lr+16nt]
//   w2f[((nt  )*2+pl)*64 + l]     (nt<4):       lane l holds W2[8lg+j][lr+16nt]
// ---------------------------------------------------------------------------
__global__ void wsetup_kernel(const float* __restrict__ W1,
                              const float* __restrict__ W2,
                              float4* __restrict__ w1f, float4* __restrict__ w2f)
{
    const int tid = threadIdx.x;
#pragma unroll
    for (int i = 0; i < 4; ++i) {
        int e = tid + 256 * i;                 // 1024 entries
        int l = e & 63, idx = e >> 6;          // idx 0..15
        int pl = idx & 1, ks = (idx >> 1) & 3, nt = idx >> 3;
        int lg = l >> 4, lr = l & 15;
        short8 v;
#pragma unroll
        for (int j = 0; j < 8; ++j) {
            ushort hi, lo;
            fsplit(W1[(32 * ks + 8 * lg + j) * HID_ + (lr + 16 * nt)], hi, lo);
            v[j] = (short)(pl ? lo : hi);
        }
        w1f[e] = *(float4*)&v;
    }
#pragma unroll
    for (int i = 0; i < 2; ++i) {
        int e = tid + 256 * i;                 // 512 entries
        int l = e & 63, idx = e >> 6;          // idx 0..7
        int pl = idx & 1, nt = idx >> 1;
        int lg = l >> 4, lr = l & 15;
        short8 v;
#pragma unroll
        for (int j = 0; j < 8; ++j) {
            ushort hi, lo;
            fsplit(W2[(8 * lg + j) * G_ + (lr + 16 * nt)], hi, lo);
            v[j] = (short)(pl ? lo : hi);
        }
        w2f[e] = *(float4*)&v;
    }
}

// ---------------------------------------------------------------------------
// Kernel A: x -> MLP1 -> MLP2 -> hp fragments. Zero __syncthreads:
// x A-frags loaded directly from global; W frags from pre-split ws (L1-hot);
// h1/hp transposed via small per-wave LDS bounce (lgkmcnt-only waits).
// Output (unchanged layout): float4 ws[((rt*2+ks)*2+pl)*64 + l], rt=row/16.
// ---------------------------------------------------------------------------
__global__ __launch_bounds__(256, 3)
void mlp_kernel(const float* __restrict__ x,
                const float* __restrict__ b1, const float* __restrict__ b2,
                const float4* __restrict__ w1f, const float4* __restrict__ w2f,
                float* __restrict__ hpws)
{
    __shared__ ushort h1b[4][2][16][32];   //  8 KB: per-wave h1 bounce
    __shared__ ushort hpb[4][2][16][64];   // 16 KB: per-wave hp bounce

    const int tid = threadIdx.x;
    const int w = tid >> 6, l = tid & 63;
    const int lg = l >> 4, lr = l & 15;
    const size_t row0 = (size_t)blockIdx.x * 64 + w * 16;

    // ---- x A-frags direct from global: lane l -> row lr, k = 32ks+8lg+j ----
    short8 ahi[4], alo[4];
    const float* xr = x + (row0 + lr) * C_IN + 8 * lg;
#pragma unroll
    for (int ks = 0; ks < 4; ++ks) {
        float4 u0 = *(const float4*)(xr + 32 * ks);
        float4 u1 = *(const float4*)(xr + 32 * ks + 4);
        ushort hi, lo;
        fsplit(u0.x, hi, lo); ahi[ks][0] = (short)hi; alo[ks][0] = (short)lo;
        fsplit(u0.y, hi, lo); ahi[ks][1] = (short)hi; alo[ks][1] = (short)lo;
        fsplit(u0.z, hi, lo); ahi[ks][2] = (short)hi; alo[ks][2] = (short)lo;
        fsplit(u0.w, hi, lo); ahi[ks][3] = (short)hi; alo[ks][3] = (short)lo;
        fsplit(u1.x, hi, lo); ahi[ks][4] = (short)hi; alo[ks][4] = (short)lo;
        fsplit(u1.y, hi, lo); ahi[ks][5] = (short)hi; alo[ks][5] = (short)lo;
        fsplit(u1.z, hi, lo); ahi[ks][6] = (short)hi; alo[ks][6] = (short)lo;
        fsplit(u1.w, hi, lo); ahi[ks][7] = (short)hi; alo[ks][7] = (short)lo;
    }

    // ---- MLP1: M=16 N=32 K=128 ----
    f32x4 h1acc[2];
#pragma unroll
    for (int nt = 0; nt < 2; ++nt) {
        float bb = b1[lr + 16 * nt];
        f32x4 acc = {bb, bb, bb, bb};
#pragma unroll
        for (int ks = 0; ks < 4; ++ks) {
            short8 bhi = *(const short8*)&w1f[((nt * 4 + ks) * 2 + 0) * 64 + l];
            short8 blo = *(const short8*)&w1f[((nt * 4 + ks) * 2 + 1) * 64 + l];
            acc = MFMA(ahi[ks], bhi, acc);
            acc = MFMA(ahi[ks], blo, acc);
            acc = MFMA(alo[ks], bhi, acc);
        }
        h1acc[nt] = acc;
    }
    // bounce h1 (in-wave transpose C/D -> A frag)
#pragma unroll
    for (int nt = 0; nt < 2; ++nt) {
#pragma unroll
        for (int r = 0; r < 4; ++r) {
            float v = lrelu(h1acc[nt][r]);
            ushort hi, lo; fsplit(v, hi, lo);
            int row = 4 * lg + r, col = lr + 16 * nt;
            int by = (2 * col) ^ ((row & 3) << 4);
            *(ushort*)((char*)&h1b[w][0][row][0] + by) = hi;
            *(ushort*)((char*)&h1b[w][1][row][0] + by) = lo;
        }
    }
    asm volatile("s_waitcnt lgkmcnt(0)" ::: "memory");
    short8 a1h, a1l;
    {
        int aby = (16 * lg) ^ ((lr & 3) << 4);
        a1h = *(short8*)((char*)&h1b[w][0][lr][0] + aby);
        a1l = *(short8*)((char*)&h1b[w][1][lr][0] + aby);
    }

    // ---- MLP2: M=16 N=64 K=32 ----
    f32x4 hpacc[4];
#pragma unroll
    for (int nt = 0; nt < 4; ++nt) {
        float bb = b2[lr + 16 * nt];
        f32x4 acc = {bb, bb, bb, bb};
        short8 bhi = *(const short8*)&w2f[(nt * 2 + 0) * 64 + l];
        short8 blo = *(const short8*)&w2f[(nt * 2 + 1) * 64 + l];
        acc = MFMA(a1h, bhi, acc);
        acc = MFMA(a1h, blo, acc);
        acc = MFMA(a1l, bhi, acc);
        hpacc[nt] = acc;
    }
    // bounce hp
#pragma unroll
    for (int nt = 0; nt < 4; ++nt) {
#pragma unroll
        for (int r = 0; r < 4; ++r) {
            float v = lrelu(hpacc[nt][r]);
            ushort hi, lo; fsplit(v, hi, lo);
            int row = 4 * lg + r, col = lr + 16 * nt;
            int by = (2 * col) ^ ((row & 7) << 4);
            *(ushort*)((char*)&hpb[w][0][row][0] + by) = hi;
            *(ushort*)((char*)&hpb[w][1][row][0] + by) = lo;
        }
    }
    asm volatile("s_waitcnt lgkmcnt(0)" ::: "memory");

    // ---- export hp A-frags (coalesced float4 stores) ----
    const size_t rt = row0 >> 4;          // t*128 + s16
    float4* outw = (float4*)hpws;
#pragma unroll
    for (int ks = 0; ks < 2; ++ks) {
        int by = (64 * ks + 16 * lg) ^ ((lr & 7) << 4);
        short8 fh = *(short8*)((char*)&hpb[w][0][lr][0] + by);
        short8 fl = *(short8*)((char*)&hpb[w][1][lr][0] + by);
        outw[((rt * 2 + ks) * 2 + 0) * 64 + l] = *(float4*)&fh;
        outw[((rt * 2 + ks) * 2 + 1) * 64 + l] = *(float4*)&fl;
    }
}

// ---------------------------------------------------------------------------
// Kernel B: GRU, single launch, 128 blocks x 16 stocks, 4 waves.
// Software-pipelined gx: gx(t+1) (register-only MFMAs on the prefetch ring)
// is computed while the h(t) ds_reads are in flight — fills the post-barrier
// LDS latency. 4-slot ring, gxA/gxB ping-pong, fully static indexing.
// One raw barrier per step (lgkmcnt-only drain; vmcnt stays in flight).
// ---------------------------------------------------------------------------
__device__ __forceinline__ void gxcalc(
    const short8 (&cur)[2][2],
    const short8 (&wih_h)[3][2], const short8 (&wih_l)[3][2],
    const float (&bih)[3], f32x4 (&agx)[3])
{
#pragma unroll
    for (int g = 0; g < 3; ++g) {
        f32x4 c0 = {bih[g], bih[g], bih[g], bih[g]};
        f32x4 c1 = {0.f, 0.f, 0.f, 0.f};
        f32x4 c2 = {0.f, 0.f, 0.f, 0.f};
        c0 = MFMA(cur[0][0], wih_h[g][0], c0);
        c1 = MFMA(cur[0][0], wih_l[g][0], c1);
        c2 = MFMA(cur[0][1], wih_h[g][0], c2);
        c0 = MFMA(cur[1][0], wih_h[g][1], c0);
        c1 = MFMA(cur[1][0], wih_l[g][1], c1);
        c2 = MFMA(cur[1][1], wih_h[g][1], c2);
        agx[g] = c0 + c1 + c2;
    }
}

__device__ __forceinline__ void gstep(
    const f32x4 (&gxin)[3], f32x4 (&gxout)[3],
    const short8 (&nring)[2][2], short8 (&pf)[2][2], int t, bool last,
    const short8* __restrict__ hpg, int b, int l, int lg, int lr, int colr,
    const short8 (&wih_h)[3][2], const short8 (&wih_l)[3][2],
    const short8 (&whh_h)[3][2], const short8 (&whh_l)[3][2],
    const float (&bih)[3], const float (&bhh)[3],
    f32x4& hprev, int& p, ushort* hbh, ushort* hbl)
{
    // 1. prefetch t+2 (stays in flight across the barrier)
    if (t + 2 < T_TOT) {
        size_t rtn = (size_t)(t + 2) * 128 + b;
#pragma unroll
        for (int ks = 0; ks < 2; ++ks)
#pragma unroll
            for (int pl = 0; pl < 2; ++pl)
                pf[ks][pl] = hpg[((rtn * 2 + ks) * 2 + pl) * 64 + l];
    }

    // 2. issue h ds_reads
    const ushort* rh = hbh + p * 1024;
    const ushort* rl = hbl + p * 1024;
    short8 ah[2], al[2];
#pragma unroll
    for (int ks = 0; ks < 2; ++ks) {
        int by = (64 * ks + 16 * lg) ^ ((lr & 7) << 4);
        ah[ks] = *(short8*)((char*)(rh + lr * 64) + by);
        al[ks] = *(short8*)((char*)(rl + lr * 64) + by);
    }

    // 3. gx(t+1): register-only MFMAs, no lgkm dependence — fills ds latency
    if (!last)
        gxcalc(nring, wih_h, wih_l, bih, gxout);

    // 4. gh = h @ W_hh^T + b_hh
    f32x4 agh[3];
#pragma unroll
    for (int g = 0; g < 3; ++g) {
        f32x4 c0 = {bhh[g], bhh[g], bhh[g], bhh[g]};
        f32x4 c1 = {0.f, 0.f, 0.f, 0.f};
        f32x4 c2 = {0.f, 0.f, 0.f, 0.f};
        c0 = MFMA(ah[0], whh_h[g][0], c0);
        c1 = MFMA(ah[0], whh_l[g][0], c1);
        c2 = MFMA(al[0], whh_h[g][0], c2);
        c0 = MFMA(ah[1], whh_h[g][1], c0);
        c1 = MFMA(ah[1], whh_l[g][1], c1);
        c2 = MFMA(al[1], whh_h[g][1], c2);
        agh[g] = c0 + c1 + c2;
    }

    // 5. gates: g0=r, g1=z, g2=n (lane-local triples)
    f32x4 hn;
#pragma unroll
    for (int r = 0; r < 4; ++r) {
        float rr = sig1(gxin[0][r] + agh[0][r]);
        float zz = sig1(gxin[1][r] + agh[1][r]);
        float nn = th1(gxin[2][r] + rr * agh[2][r]);
        hn[r] = fmaf(zz, hprev[r] - nn, nn);
    }

    // 6. write h_new -> buf[p^1]
    ushort* wh = hbh + (p ^ 1) * 1024;
    ushort* wl = hbl + (p ^ 1) * 1024;
#pragma unroll
    for (int r = 0; r < 4; ++r) {
        ushort hi, lo; fsplit(hn[r], hi, lo);
        int row = 4 * lg + r;
        int by = (2 * colr) ^ ((row & 7) << 4);
        *(ushort*)((char*)(wh + row * 64) + by) = hi;
        *(ushort*)((char*)(wl + row * 64) + by) = lo;
    }
    hprev = hn;

    // 7. LDS-only drain + raw barrier (vmcnt NOT drained)
    asm volatile("s_waitcnt lgkmcnt(0)\n\ts_barrier" ::: "memory");
    p ^= 1;
}

__global__ __launch_bounds__(256, 1)
void gru_kernel(const float* __restrict__ hpws_f,
                const float* __restrict__ W_ih, const float* __restrict__ W_hh,
                const float* __restrict__ b_ih, const float* __restrict__ b_hh,
                float* __restrict__ out)
{
    __shared__ ushort hbh_s[2][16][64], hbl_s[2][16][64];   // ping-pong h planes, 8 KB

    const int tid = threadIdx.x;
    const int w = tid >> 6, l = tid & 63;
    const int lg = l >> 4, lr = l & 15;
    const int colr = 16 * w + lr;        // latent col (0..63)
    const int b = blockIdx.x;            // stock tile (16 stocks)
    ushort* hbh = &hbh_s[0][0][0];
    ushort* hbl = &hbl_s[0][0][0];

    // ---- persistent B-fragments (W rows contiguous in k) ----
    short8 wih_h[3][2], wih_l[3][2], whh_h[3][2], whh_l[3][2];
    float bih[3], bhh[3];
#pragma unroll
    for (int g = 0; g < 3; ++g) {
        int n = colr + 64 * g;
        bih[g] = b_ih[n];
        bhh[g] = b_hh[n];
#pragma unroll
        for (int ks = 0; ks < 2; ++ks) {
            const float* pp = W_ih + n * 64 + 32 * ks + 8 * lg;
            const float* qq = W_hh + n * 64 + 32 * ks + 8 * lg;
            short8 ph, pl, qh, ql;
#pragma unroll
            for (int j = 0; j < 8; ++j) {
                ushort hi, lo;
                fsplit(pp[j], hi, lo); ph[j] = (short)hi; pl[j] = (short)lo;
                fsplit(qq[j], hi, lo); qh[j] = (short)hi; ql[j] = (short)lo;
            }
            wih_h[g][ks] = ph; wih_l[g][ks] = pl;
            whh_h[g][ks] = qh; whh_l[g][ks] = ql;
        }
    }

    // ---- h0 = 0 ----
    f32x4 hprev = {0.f, 0.f, 0.f, 0.f};
#pragma unroll
    for (int r = 0; r < 4; ++r) {
        int row = 4 * lg + r;
        int by = (2 * colr) ^ ((row & 7) << 4);
        *(ushort*)((char*)(hbh + row * 64) + by) = 0;
        *(ushort*)((char*)(hbl + row * 64) + by) = 0;
    }
    asm volatile("s_waitcnt lgkmcnt(0)\n\ts_barrier" ::: "memory");
    int p = 0;

    // ---- prefetch ring prologue: t=0 -> ring[0], t=1 -> ring[1] ----
    const short8* hpg = (const short8*)hpws_f;
    short8 ring[4][2][2];
#pragma unroll
    for (int tt = 0; tt < 2; ++tt) {
        size_t rt = (size_t)tt * 128 + b;
#pragma unroll
        for (int ks = 0; ks < 2; ++ks)
#pragma unroll
            for (int pl = 0; pl < 2; ++pl)
                ring[tt][ks][pl] = hpg[((rt * 2 + ks) * 2 + pl) * 64 + l];
    }

    f32x4 gxA[3], gxB[3];
    gxcalc(ring[0], wih_h, wih_l, bih, gxA);   // gx for t=0

    // ---- main loop: 63 x 4 steps (t = 0..251), static ring/gx indices ----
    for (int tb = 0; tb < 252; tb += 4) {
        gstep(gxA, gxB, ring[1], ring[2], tb + 0, false, hpg, b, l, lg, lr, colr,
              wih_h, wih_l, whh_h, whh_l, bih, bhh, hprev, p, hbh, hbl);
        gstep(gxB, gxA, ring[2], ring[3], tb + 1, false, hpg, b, l, lg, lr, colr,
              wih_h, wih_l, whh_h, whh_l, bih, bhh, hprev, p, hbh, hbl);
        gstep(gxA, gxB, ring[3], ring[0], tb + 2, false, hpg, b, l, lg, lr, colr,
              wih_h, wih_l, whh_h, whh_l, bih, bhh, hprev, p, hbh, hbl);
        gstep(gxB, gxA, ring[0], ring[1], tb + 3, false, hpg, b, l, lg, lr, colr,
              wih_h, wih_l, whh_h, whh_l, bih, bhh, hprev, p, hbh, hbl);
    }
    // epilogue t = 252..255 (prefetch guards fold off; t=255 skips gx_nxt)
    gstep(gxA, gxB, ring[1], ring[2], 252, false, hpg, b, l, lg, lr, colr,
          wih_h, wih_l, whh_h, whh_l, bih, bhh, hprev, p, hbh, hbl);
    gstep(gxB, gxA, ring[2], ring[3], 253, false, hpg, b, l, lg, lr, colr,
          wih_h, wih_l, whh_h, whh_l, bih, bhh, hprev, p, hbh, hbl);
    gstep(gxA, gxB, ring[3], ring[0], 254, false, hpg, b, l, lg, lr, colr,
          wih_h, wih_l, whh_h, whh_l, bih, bhh, hprev, p, hbh, hbl);
    gstep(gxB, gxA, ring[0], ring[1], 255, true, hpg, b, l, lg, lr, colr,
          wih_h, wih_l, whh_h, whh_l, bih, bhh, hprev, p, hbh, hbl);

#pragma unroll
    for (int r = 0; r < 4; ++r)
        out[(16 * b + 4 * lg + r) * 64 + colr] = hprev[r];
}

// ---------------------------------------------------------------------------
extern "C" void kernel_launch(void* const* d_in, const int* in_sizes, int n_in,
                              void* d_out, int out_size, void* d_ws, size_t ws_size,
                              hipStream_t stream)
{
    const float* x    = (const float*)d_in[0];
    const float* W1   = (const float*)d_in[1];
    const float* b1   = (const float*)d_in[2];
    const float* W2   = (const float*)d_in[3];
    const float* b2   = (const float*)d_in[4];
    const float* W_ih = (const float*)d_in[5];
    const float* W_hh = (const float*)d_in[6];
    const float* b_ih = (const float*)d_in[7];
    const float* b_hh = (const float*)d_in[8];
    float* out = (float*)d_out;

    // ws layout: [0,16K) w1f | [16K,24K) w2f | [32K, 32K+128M) hp frags
    float4* w1f = (float4*)d_ws;
    float4* w2f = w1f + 1024;
    float*  hp  = (float*)((char*)d_ws + 32 * 1024);

    wsetup_kernel<<<1, 256, 0, stream>>>(W1, W2, w1f, w2f);
    mlp_kernel<<<(T_TOT * S_TOT) / 64, 256, 0, stream>>>(x, b1, b2, w1f, w2f, hp);
    gru_kernel<<<S_TOT / 16, 256, 0, stream>>>(hp, W_ih, W_hh, b_ih, b_hh, out);
}